// Round 8
// baseline (117.898 us; speedup 1.0000x reference)
//
#include <hip/hip_runtime.h>

typedef float float2v __attribute__((ext_vector_type(2)));
typedef float float4v __attribute__((ext_vector_type(4)));

#define NN 1024

// ---------------- K1: fused ac1 + pair32(relu, pk-f32) + ac2 ----------------
// 512 blocks x 256. Wave owns row i = blk*4+wave. (round-7 verified code)
// Block 0 additionally zeroes k2's sync cells (counter, flag, Sg).
__global__ __launch_bounds__(256) void k1_pair32_ac2(
    const float* __restrict__ x,  const float* __restrict__ W1, const float* __restrict__ b1,
    const float* __restrict__ W2, const float* __restrict__ b2,
    float* __restrict__ a2g, float* __restrict__ c2g, unsigned int* __restrict__ syncw)
{
    __shared__ float xbuf[3072];        // whole batch x, 12 KB
    __shared__ float cbuf[8192];        // 256 rows x 32, 32 KB
    __shared__ float rowbuf[4][32];

    const int tid  = threadIdx.x;
    const int wave = tid >> 6, lane = tid & 63;
    const int blk  = blockIdx.x;
    if (blk == 0 && tid < 8) syncw[tid] = 0u;   // counter, flag, Sg[6]

    const int i  = blk * 4 + wave;      // 0..2047
    const int b  = i >> 10;
    const int il = i & 1023;
    const int js = lane >> 4;           // 0..3 (j-quarter)
    const int fp = lane & 15;           // f-pair index (f = 2fp, 2fp+1)

    // stage x batch to LDS
    const float4v* xb4 = (const float4v*)(x + b * 3072);
    {
        float4v* xd = (float4v*)xbuf;
        #pragma unroll
        for (int n = 0; n < 3; ++n) xd[tid + n * 256] = xb4[tid + n * 256];
    }
    __syncthreads();

    const float xi0 = xbuf[il*3+0], xi1 = xbuf[il*3+1], xi2 = xbuf[il*3+2];
    const float2v* W1v = (const float2v*)W1;
    const float2v* b1v = (const float2v*)b1;
    float2v a  = xi0*W1v[0*16+fp] + xi1*W1v[1*16+fp] + xi2*W1v[2*16+fp];
    float2v cs = xi0*W1v[3*16+fp] + xi1*W1v[4*16+fp] + xi2*W1v[5*16+fp] + b1v[fp];

    // c-recompute assignment: thread (fp2, r0); rows r = r0 + k*16 within tile
    const int fp2 = tid & 15, r0 = tid >> 4;
    const float2v w3 = W1v[3*16+fp2], w4 = W1v[4*16+fp2], w5 = W1v[5*16+fp2];
    const float2v bb = b1v[fp2];

    float2v acc = (float2v)0.f;
    float2v* cb2w = (float2v*)cbuf;
    const float2v* cb2 = (const float2v*)cbuf;
    for (int tile = 0; tile < NN; tile += 256) {
        #pragma unroll
        for (int k = 0; k < 16; ++k) {
            int r = r0 + k * 16;
            int g = tile + r;
            float y0 = xbuf[g*3+0], y1 = xbuf[g*3+1], y2 = xbuf[g*3+2];
            cb2w[r*16 + fp2] = y0*w3 + y1*w4 + y2*w5 + bb;
        }
        __syncthreads();
        #pragma unroll 8
        for (int k = 0; k < 64; ++k) {
            float2v c = cb2[(4*k + js)*16 + fp];
            acc += __builtin_elementwise_max(a + c, (float2v)0.f);
        }
        __syncthreads();
    }
    // reduce across the 4 js groups (lane bits 4,5)
    acc.x += __shfl_xor(acc.x, 16);  acc.y += __shfl_xor(acc.y, 16);
    acc.x += __shfl_xor(acc.x, 32);  acc.y += __shfl_xor(acc.y, 32);

    float2v self = __builtin_elementwise_max(a + cs, (float2v)0.f);
    float2v res  = (acc - self) * (1.0f/1023.0f);
    if (js == 0) ((float2v*)rowbuf[wave])[fp] = res;
    __syncthreads();

    // ---- ac2 epilogue: h-row (32) @ W2 (64x64) + b2 ----
    float av = 0.f, cv = b2[lane];
    #pragma unroll
    for (int d = 0; d < 32; ++d) {
        float hv = rowbuf[wave][d];     // LDS broadcast
        av += hv * W2[d*64 + lane];
        cv += hv * W2[(32 + d)*64 + lane];
    }
    a2g[i*64 + lane] = av;
    c2g[i*64 + lane] = cv;
}

// ---------------- K2: pair-sum F=64 + projection + last-block S (no k3) ----------------
// 512 blocks x 256, ~4 KB LDS (all co-resident: capacity >= 8 blocks/CU).
// Block owns rows i0..i0+3; all 4 waves split j 8-ways (j = 8k + 2*wave + jq).
// c2 read DIRECTLY from L2 (no LDS staging). Out-writes deferred until the
// global S (colsum @ W3bot) is known via agent-scope last-block reduction.
__global__ __launch_bounds__(256) void k2_pair64_final(
    const float* __restrict__ a2g, const float* __restrict__ c2g,
    const float* __restrict__ W3, const float* __restrict__ b3,
    float* __restrict__ out, float* __restrict__ partials,
    unsigned int* __restrict__ syncw)
{
    __shared__ float2v pacc[4][4][32];  // [wave][row][fp], 4 KB
    __shared__ float qpart[4][3];
    __shared__ float redbuf[4][6];
    __shared__ float sS[6];
    __shared__ unsigned int sLast;

    const int tid  = threadIdx.x;
    const int wave = tid >> 6, lane = tid & 63;
    const int blk  = blockIdx.x;        // 0..511

    const int i0 = blk * 4;
    const int b  = blk >> 8;            // batch
    const int jq = lane >> 5, fp = lane & 31;
    const float inv = 1.0f/1023.0f;

    unsigned int* counter = syncw;
    unsigned int* flag    = syncw + 1;
    float*        Sg      = (float*)(syncw + 2);

    const float* cb = c2g + b * (NN * 64);
    const float2v* cbv = (const float2v*)cb;
    const float2v* a2v = (const float2v*)a2g;
    const float2v a0 = a2v[(i0+0)*32 + fp];
    const float2v a1 = a2v[(i0+1)*32 + fp];
    const float2v a2 = a2v[(i0+2)*32 + fp];
    const float2v a3 = a2v[(i0+3)*32 + fp];
    float2v s0 = (float2v)0.f, s1 = (float2v)0.f, s2 = (float2v)0.f, s3 = (float2v)0.f;

    const int jbase = 2*wave + jq;              // this thread's j residue mod 8
    const float2v* cj = cbv + jbase*32 + fp;    // stride 8 rows = 256 float2 per k
    #pragma unroll 16
    for (int k = 0; k < 128; ++k) {
        float2v c = cj[k * 256];
        s0 += __builtin_elementwise_max(a0 + c, (float2v)0.f);
        s1 += __builtin_elementwise_max(a1 + c, (float2v)0.f);
        s2 += __builtin_elementwise_max(a2 + c, (float2v)0.f);
        s3 += __builtin_elementwise_max(a3 + c, (float2v)0.f);
    }
    // fold jq (lane bit 5)
    s0.x += __shfl_xor(s0.x, 32);  s0.y += __shfl_xor(s0.y, 32);
    s1.x += __shfl_xor(s1.x, 32);  s1.y += __shfl_xor(s1.y, 32);
    s2.x += __shfl_xor(s2.x, 32);  s2.y += __shfl_xor(s2.y, 32);
    s3.x += __shfl_xor(s3.x, 32);  s3.y += __shfl_xor(s3.y, 32);
    if (jq == 0) {
        pacc[wave][0][fp] = s0;  pacc[wave][1][fp] = s1;
        pacc[wave][2][fp] = s2;  pacc[wave][3][fp] = s3;
    }
    __syncthreads();

    // ---- finalize: wave w owns row i0+w ----
    const int i = i0 + wave;
    float2v racc = pacc[0][wave][fp] + pacc[1][wave][fp]
                 + pacc[2][wave][fp] + pacc[3][wave][fp];
    float2v ai   = a2v[i*32 + fp];
    float2v self = __builtin_elementwise_max(ai + cbv[(i & 1023)*32 + fp], (float2v)0.f);
    float2v res  = (racc - self) * inv;

    // projection: per-lane f-pair; butterfly within each 32-lane half
    float y[3], q[3];
    #pragma unroll
    for (int t = 0; t < 3; ++t) {
        float wt0 = W3[(2*fp)*3 + t],   wb0 = W3[(64 + 2*fp)*3 + t];
        float wt1 = W3[(2*fp+1)*3 + t], wb1 = W3[(64 + 2*fp+1)*3 + t];
        y[t] = res.x*(wt0 - wb0*inv) + res.y*(wt1 - wb1*inv);
        q[t] = res.x*wb0 + res.y*wb1;
    }
    #pragma unroll
    for (int off = 1; off < 32; off <<= 1) {
        #pragma unroll
        for (int t = 0; t < 3; ++t) {
            y[t] += __shfl_xor(y[t], off);
            q[t] += __shfl_xor(q[t], off);
        }
    }
    if (lane == 0) { qpart[wave][0] = q[0]; qpart[wave][1] = q[1]; qpart[wave][2] = q[2]; }
    __syncthreads();

    // ---- publish partials (agent scope, no L2 writeback needed) ----
    if (tid < 3) {
        float p = qpart[0][tid] + qpart[1][tid] + qpart[2][tid] + qpart[3][tid];
        __hip_atomic_store(&partials[blk*3 + tid], p, __ATOMIC_RELAXED, __HIP_MEMORY_SCOPE_AGENT);
    }
    asm volatile("s_waitcnt vmcnt(0)" ::: "memory");   // drain own stores to coherence point
    __syncthreads();
    if (tid == 0) {
        unsigned int old = __hip_atomic_fetch_add(counter, 1u, __ATOMIC_RELAXED, __HIP_MEMORY_SCOPE_AGENT);
        sLast = (old == 511u) ? 1u : 0u;
    }
    __syncthreads();

    if (sLast) {
        // last block: reduce 512x3 partials -> S[2][3]
        float p0[3], p1[3];
        #pragma unroll
        for (int t = 0; t < 3; ++t) {
            p0[t] = __hip_atomic_load(&partials[tid*3 + t],        __ATOMIC_RELAXED, __HIP_MEMORY_SCOPE_AGENT);
            p1[t] = __hip_atomic_load(&partials[(256+tid)*3 + t],  __ATOMIC_RELAXED, __HIP_MEMORY_SCOPE_AGENT);
        }
        #pragma unroll
        for (int off = 1; off < 64; off <<= 1) {
            #pragma unroll
            for (int t = 0; t < 3; ++t) {
                p0[t] += __shfl_xor(p0[t], off);
                p1[t] += __shfl_xor(p1[t], off);
            }
        }
        if (lane == 0) {
            #pragma unroll
            for (int t = 0; t < 3; ++t) { redbuf[wave][t] = p0[t]; redbuf[wave][3+t] = p1[t]; }
        }
        __syncthreads();
        if (tid < 6) {
            float v = redbuf[0][tid] + redbuf[1][tid] + redbuf[2][tid] + redbuf[3][tid];
            __hip_atomic_store(&Sg[tid], v, __ATOMIC_RELAXED, __HIP_MEMORY_SCOPE_AGENT);
        }
        asm volatile("s_waitcnt vmcnt(0)" ::: "memory");
        __syncthreads();
        if (tid == 0)
            __hip_atomic_store(flag, 1u, __ATOMIC_RELAXED, __HIP_MEMORY_SCOPE_AGENT);
    }

    // ---- wait for S (bounded spin; all 512 blocks are co-resident) ----
    if (tid == 0) {
        int it = 0;
        while (__hip_atomic_load(flag, __ATOMIC_RELAXED, __HIP_MEMORY_SCOPE_AGENT) == 0u) {
            __builtin_amdgcn_s_sleep(1);
            if (++it > (1 << 18)) break;    // bounded: fail loud (wrong result), never hang
        }
    }
    __syncthreads();
    if (tid < 6) sS[tid] = __hip_atomic_load(&Sg[tid], __ATOMIC_RELAXED, __HIP_MEMORY_SCOPE_AGENT);
    __syncthreads();

    if (lane == 0) {
        out[i*3+0] = y[0] + b3[0] + sS[b*3+0] * inv;
        out[i*3+1] = y[1] + b3[1] + sS[b*3+1] * inv;
        out[i*3+2] = y[2] + b3[2] + sS[b*3+2] * inv;
    }
}

extern "C" void kernel_launch(void* const* d_in, const int* in_sizes, int n_in,
                              void* d_out, int out_size, void* d_ws, size_t ws_size,
                              hipStream_t stream) {
    const float* x  = (const float*)d_in[0];
    const float* W1 = (const float*)d_in[1];
    const float* b1 = (const float*)d_in[2];
    const float* W2 = (const float*)d_in[3];
    const float* b2 = (const float*)d_in[4];
    const float* W3 = (const float*)d_in[5];
    const float* b3 = (const float*)d_in[6];
    float* out = (float*)d_out;

    float* ws = (float*)d_ws;
    float* a2g      = ws;                    // 131072 floats
    float* c2g      = a2g + 131072;          // 131072 floats
    float* partials = c2g + 131072;          // 1536 floats
    unsigned int* syncw = (unsigned int*)(partials + 1536);  // [0]=cnt [1]=flag [2..7]=Sg

    k1_pair32_ac2<<<512, 256, 0, stream>>>(x, W1, b1, W2, b2, a2g, c2g, syncw);
    k2_pair64_final<<<512, 256, 0, stream>>>(a2g, c2g, W3, b3, out, partials, syncw);
}

// Round 9
// 104.354 us; speedup vs baseline: 1.1298x; 1.1298x over previous
//
#include <hip/hip_runtime.h>

typedef float float2v __attribute__((ext_vector_type(2)));
typedef float float4v __attribute__((ext_vector_type(4)));

#define NN 1024

// ---------------- K1: fused ac1 + pair32(relu, pk-f32) + ac2 ----------------
// 512 blocks x 256. Wave owns row i = blk*4+wave.
// x batch (12 KB) staged to LDS once; c1-tiles recomputed from LDS-x (pk);
// j-loop 4-way js split, float2 lanes. Epilogue: row @ W2 -> a2,c2.
__global__ __launch_bounds__(256) void k1_pair32_ac2(
    const float* __restrict__ x,  const float* __restrict__ W1, const float* __restrict__ b1,
    const float* __restrict__ W2, const float* __restrict__ b2,
    float* __restrict__ a2g, float* __restrict__ c2g)
{
    __shared__ float xbuf[3072];        // whole batch x, 12 KB
    __shared__ float cbuf[8192];        // 256 rows x 32, 32 KB
    __shared__ float rowbuf[4][32];

    const int tid  = threadIdx.x;
    const int wave = tid >> 6, lane = tid & 63;
    const int blk  = blockIdx.x;

    const int i  = blk * 4 + wave;      // 0..2047
    const int b  = i >> 10;
    const int il = i & 1023;
    const int js = lane >> 4;           // 0..3 (j-quarter)
    const int fp = lane & 15;           // f-pair index (f = 2fp, 2fp+1)

    // stage x batch to LDS
    const float4v* xb4 = (const float4v*)(x + b * 3072);
    {
        float4v* xd = (float4v*)xbuf;
        #pragma unroll
        for (int n = 0; n < 3; ++n) xd[tid + n * 256] = xb4[tid + n * 256];
    }
    __syncthreads();

    const float xi0 = xbuf[il*3+0], xi1 = xbuf[il*3+1], xi2 = xbuf[il*3+2];
    const float2v* W1v = (const float2v*)W1;
    const float2v* b1v = (const float2v*)b1;
    float2v a  = xi0*W1v[0*16+fp] + xi1*W1v[1*16+fp] + xi2*W1v[2*16+fp];
    float2v cs = xi0*W1v[3*16+fp] + xi1*W1v[4*16+fp] + xi2*W1v[5*16+fp] + b1v[fp];

    // c-recompute assignment: thread (fp2, r0); rows r = r0 + k*16 within tile
    const int fp2 = tid & 15, r0 = tid >> 4;
    const float2v w3 = W1v[3*16+fp2], w4 = W1v[4*16+fp2], w5 = W1v[5*16+fp2];
    const float2v bb = b1v[fp2];

    float2v acc = (float2v)0.f;
    float2v* cb2w = (float2v*)cbuf;
    const float2v* cb2 = (const float2v*)cbuf;
    for (int tile = 0; tile < NN; tile += 256) {
        #pragma unroll
        for (int k = 0; k < 16; ++k) {
            int r = r0 + k * 16;
            int g = tile + r;
            float y0 = xbuf[g*3+0], y1 = xbuf[g*3+1], y2 = xbuf[g*3+2];
            cb2w[r*16 + fp2] = y0*w3 + y1*w4 + y2*w5 + bb;
        }
        __syncthreads();
        #pragma unroll 8
        for (int k = 0; k < 64; ++k) {
            float2v c = cb2[(4*k + js)*16 + fp];
            acc += __builtin_elementwise_max(a + c, (float2v)0.f);
        }
        __syncthreads();
    }
    // reduce across the 4 js groups (lane bits 4,5)
    acc.x += __shfl_xor(acc.x, 16);  acc.y += __shfl_xor(acc.y, 16);
    acc.x += __shfl_xor(acc.x, 32);  acc.y += __shfl_xor(acc.y, 32);

    float2v self = __builtin_elementwise_max(a + cs, (float2v)0.f);
    float2v res  = (acc - self) * (1.0f/1023.0f);
    if (js == 0) ((float2v*)rowbuf[wave])[fp] = res;
    __syncthreads();

    // ---- ac2 epilogue: h-row (32) @ W2 (64x64) + b2 ----
    float av = 0.f, cv = b2[lane];
    #pragma unroll
    for (int d = 0; d < 32; ++d) {
        float hv = rowbuf[wave][d];     // LDS broadcast
        av += hv * W2[d*64 + lane];
        cv += hv * W2[(32 + d)*64 + lane];
    }
    a2g[i*64 + lane] = av;
    c2g[i*64 + lane] = cv;
}

// ---------------- K2: pair-sum F=64 (pk-f32) + fused final projection ----------------
// 512 blocks x 256, 2 blocks/CU. Block owns rows i0..i0+3; ALL 4 waves process
// the same 4 rows, splitting j 8 ways (wave w, lane-half jq): j = 8k + 2w + jq.
// Each ds_read of c[j] feeds 12 pk-VALU (4 rows). Partial accs combined via LDS;
// wave w finalizes row i0+w, projects through W3 (butterfly) -> out, q-partials.
__global__ __launch_bounds__(256) void k2_pair64_final(
    const float* __restrict__ a2g, const float* __restrict__ c2g,
    const float* __restrict__ W3, const float* __restrict__ b3,
    float* __restrict__ out, float* __restrict__ partials)
{
    __shared__ float cbuf[8192];        // 128 j-rows x 64 f, 32 KB
    __shared__ float2v pacc[4][4][32];  // [wave][row][fp], 4 KB
    __shared__ float qpart[4][3];

    const int tid  = threadIdx.x;
    const int wave = tid >> 6, lane = tid & 63;
    const int blk  = blockIdx.x;        // 0..511

    const int i0 = blk * 4;
    const int b  = blk >> 8;            // batch
    const int jq = lane >> 5, fp = lane & 31;

    const float* cb = c2g + b * (NN * 64);
    const float2v* a2v = (const float2v*)a2g;
    const float2v a0 = a2v[(i0+0)*32 + fp];
    const float2v a1 = a2v[(i0+1)*32 + fp];
    const float2v a2 = a2v[(i0+2)*32 + fp];
    const float2v a3 = a2v[(i0+3)*32 + fp];
    float2v s0 = (float2v)0.f, s1 = (float2v)0.f, s2 = (float2v)0.f, s3 = (float2v)0.f;

    const float4v* src = (const float4v*)cb;    // 16 float4 per j-row
    const float2v* cb2 = (const float2v*)cbuf;
    const int jbase = 2*wave + jq;              // this thread's j residue mod 8
    for (int tile = 0; tile < NN; tile += 128) {
        const float4v* sp = src + tile * 16;
        float4v* dst = (float4v*)cbuf;
        #pragma unroll
        for (int n = 0; n < 8; ++n) dst[tid + n*256] = sp[tid + n*256];
        __syncthreads();
        #pragma unroll
        for (int k = 0; k < 16; ++k) {
            float2v c = cb2[(8*k + jbase)*32 + fp];
            s0 += __builtin_elementwise_max(a0 + c, (float2v)0.f);
            s1 += __builtin_elementwise_max(a1 + c, (float2v)0.f);
            s2 += __builtin_elementwise_max(a2 + c, (float2v)0.f);
            s3 += __builtin_elementwise_max(a3 + c, (float2v)0.f);
        }
        __syncthreads();
    }
    // fold jq (lane bit 5)
    s0.x += __shfl_xor(s0.x, 32);  s0.y += __shfl_xor(s0.y, 32);
    s1.x += __shfl_xor(s1.x, 32);  s1.y += __shfl_xor(s1.y, 32);
    s2.x += __shfl_xor(s2.x, 32);  s2.y += __shfl_xor(s2.y, 32);
    s3.x += __shfl_xor(s3.x, 32);  s3.y += __shfl_xor(s3.y, 32);
    if (jq == 0) {
        pacc[wave][0][fp] = s0;  pacc[wave][1][fp] = s1;
        pacc[wave][2][fp] = s2;  pacc[wave][3][fp] = s3;
    }
    __syncthreads();

    // ---- finalize: wave w owns row i0+w ----
    const int i = i0 + wave;
    float2v racc = pacc[0][wave][fp] + pacc[1][wave][fp]
                 + pacc[2][wave][fp] + pacc[3][wave][fp];
    const float2v* cbv = (const float2v*)cb;
    const float inv = 1.0f/1023.0f;
    float2v ai   = a2v[i*32 + fp];
    float2v self = __builtin_elementwise_max(ai + cbv[(i & 1023)*32 + fp], (float2v)0.f);
    float2v res  = (racc - self) * inv;

    // final projection: per-lane f-pair; butterfly within each 32-lane half
    // (both halves hold identical res -> each half's 32-lane sum is the full sum)
    float y[3], q[3];
    #pragma unroll
    for (int t = 0; t < 3; ++t) {
        float wt0 = W3[(2*fp)*3 + t],   wb0 = W3[(64 + 2*fp)*3 + t];
        float wt1 = W3[(2*fp+1)*3 + t], wb1 = W3[(64 + 2*fp+1)*3 + t];
        y[t] = res.x*(wt0 - wb0*inv) + res.y*(wt1 - wb1*inv);
        q[t] = res.x*wb0 + res.y*wb1;
    }
    #pragma unroll
    for (int off = 1; off < 32; off <<= 1) {
        #pragma unroll
        for (int t = 0; t < 3; ++t) {
            y[t] += __shfl_xor(y[t], off);
            q[t] += __shfl_xor(q[t], off);
        }
    }
    if (lane == 0) {
        out[i*3+0] = y[0] + b3[0];
        out[i*3+1] = y[1] + b3[1];
        out[i*3+2] = y[2] + b3[2];
        qpart[wave][0] = q[0];  qpart[wave][1] = q[1];  qpart[wave][2] = q[2];
    }
    __syncthreads();
    if (tid < 3)
        partials[blk*3 + tid] = qpart[0][tid] + qpart[1][tid] + qpart[2][tid] + qpart[3][tid];
}

// ---------------- K3: reduce partials -> S; broadcast add ----------------
// 8 blocks x 256; block blk: batch b=blk>>2, rows (blk&3)*256 + tid of that batch.
__global__ __launch_bounds__(256) void k3_final(
    const float* __restrict__ partials, float* __restrict__ out)
{
    __shared__ float red[4][3];

    const int tid  = threadIdx.x;
    const int wave = tid >> 6, lane = tid & 63;
    const int blk  = blockIdx.x;
    const int b = blk >> 2;

    // 256 threads <-> 256 k2-blocks of this batch
    const float* pb = partials + b * 256 * 3;
    float s0 = pb[tid*3+0], s1 = pb[tid*3+1], s2 = pb[tid*3+2];
    #pragma unroll
    for (int off = 32; off; off >>= 1) {
        s0 += __shfl_xor(s0, off);  s1 += __shfl_xor(s1, off);  s2 += __shfl_xor(s2, off);
    }
    if (lane == 0) { red[wave][0] = s0; red[wave][1] = s1; red[wave][2] = s2; }
    __syncthreads();
    float S0 = (red[0][0]+red[1][0]+red[2][0]+red[3][0]) * (1.0f/1023.0f);
    float S1 = (red[0][1]+red[1][1]+red[2][1]+red[3][1]) * (1.0f/1023.0f);
    float S2 = (red[0][2]+red[1][2]+red[2][2]+red[3][2]) * (1.0f/1023.0f);

    const int i = b * NN + (blk & 3) * 256 + tid;   // global row
    out[i*3+0] += S0;
    out[i*3+1] += S1;
    out[i*3+2] += S2;
}

extern "C" void kernel_launch(void* const* d_in, const int* in_sizes, int n_in,
                              void* d_out, int out_size, void* d_ws, size_t ws_size,
                              hipStream_t stream) {
    const float* x  = (const float*)d_in[0];
    const float* W1 = (const float*)d_in[1];
    const float* b1 = (const float*)d_in[2];
    const float* W2 = (const float*)d_in[3];
    const float* b2 = (const float*)d_in[4];
    const float* W3 = (const float*)d_in[5];
    const float* b3 = (const float*)d_in[6];
    float* out = (float*)d_out;

    float* ws = (float*)d_ws;
    float* a2g      = ws;                    // 131072 floats
    float* c2g      = a2g + 131072;          // 131072 floats
    float* partials = c2g + 131072;          // 1536 floats

    k1_pair32_ac2<<<512, 256, 0, stream>>>(x, W1, b1, W2, b2, a2g, c2g);
    k2_pair64_final<<<512, 256, 0, stream>>>(a2g, c2g, W3, b3, out, partials);
    k3_final<<<8, 256, 0, stream>>>(partials, out);
}